// Round 21
// baseline (253.046 us; speedup 1.0000x reference)
//
#include <hip/hip_runtime.h>

#define T_LEN 2048
#define C_DIM 768
#define NH 12
#define HD 64
#define B_SZ 4
#define M_ROWS (B_SZ * T_LEN)  // 8192
#define WSZ (C_DIM * C_DIM)    // 589824
#define CH 512                 // attn LDS chunk stride: 1024B exact -> 32KB LDS, 0 bank conflicts

typedef __bf16 bf16x8 __attribute__((ext_vector_type(8)));
typedef float f32x4 __attribute__((ext_vector_type(4)));
typedef float f32x16 __attribute__((ext_vector_type(16)));

__device__ __forceinline__ unsigned short f2bf(float f) {
    union { __bf16 b; unsigned short u; } c;
    c.b = (__bf16)f;
    return c.u;
}

__device__ __forceinline__ float fast_exp2(float x) {
    float r;
    asm("v_exp_f32 %0, %1" : "=v"(r) : "v"(x));
    return r;
}

// pack two f32 -> one u32 of 2x bf16 (lo=a, hi=b)
__device__ __forceinline__ unsigned cvt_pk_bf16(float a, float b) {
    unsigned r;
    asm("v_cvt_pk_bf16_f32 %0, %1, %2" : "=v"(r) : "v"(a), "v"(b));
    return r;
}

// exchange a[lanes 32..63] with b[lanes 0..31]
__device__ __forceinline__ void perml32_swap(unsigned& a, unsigned& b) {
    asm("v_permlane32_swap_b32 %0, %1" : "+v"(a), "+v"(b));
}

// async global->LDS, 16B/lane; LDS dest = uniform base + lane*16.
__device__ __forceinline__ void gl2lds16(const void* g, void* l) {
    __builtin_amdgcn_global_load_lds(
        (const __attribute__((address_space(1))) unsigned int*)g,
        (__attribute__((address_space(3))) unsigned int*)l, 16, 0, 0);
}

// ---------------------------------------------------------------------------
// x [8192][768] fp32 -> bf16 row-major
// ---------------------------------------------------------------------------
__global__ __launch_bounds__(256) void conv_x(const float* __restrict__ x,
                                              unsigned short* __restrict__ xb)
{
    const int i = blockIdx.x * 256 + threadIdx.x;
    float4 v = ((const float4*)x)[i];
    ushort4 o;
    o.x = f2bf(v.x); o.y = f2bf(v.y); o.z = f2bf(v.z); o.w = f2bf(v.w);
    ((ushort4*)xb)[i] = o;
}

// ---------------------------------------------------------------------------
// W [768][768] fp32 (k-major) -> Wt [768][768] bf16 (n-major, i.e. W^T)
// ---------------------------------------------------------------------------
__global__ __launch_bounds__(256) void conv_wt(
    const float* __restrict__ W0, const float* __restrict__ W1,
    const float* __restrict__ W2, const float* __restrict__ W3,
    unsigned short* __restrict__ WtAll)
{
    __shared__ float tile[32][33];
    const int z = blockIdx.z;
    const float* W = (z == 0) ? W0 : (z == 1) ? W1 : (z == 2) ? W2 : W3;
    unsigned short* out = WtAll + (size_t)z * WSZ;
    const int k0 = blockIdx.x * 32, n0 = blockIdx.y * 32;
    const int r = threadIdx.x >> 3, c4 = (threadIdx.x & 7) * 4;
    float4 v = *(const float4*)&W[(size_t)(k0 + r) * C_DIM + n0 + c4];
    tile[r][c4 + 0] = v.x;
    tile[r][c4 + 1] = v.y;
    tile[r][c4 + 2] = v.z;
    tile[r][c4 + 3] = v.w;
    __syncthreads();
    ushort4 o;
    o.x = f2bf(tile[c4 + 0][r]);
    o.y = f2bf(tile[c4 + 1][r]);
    o.z = f2bf(tile[c4 + 2][r]);
    o.w = f2bf(tile[c4 + 3][r]);
    *(ushort4*)&out[(size_t)(n0 + r) * C_DIM + k0 + c4] = o;
}

// ---------------------------------------------------------------------------
// Tiled bf16 MFMA GEMM, tile 128xBN, BK=64, 4 waves (2x2).
// MODE 0 (BN=192, fused QKV): SINGLE-buffered LDS (40KB), 3 blocks/CU all
//   resident (grid 768 = 3/CU exact). Barrier order REORDERED this round:
//   barrier A (drain staging) -> ds_read frags -> barrier B (reads retired)
//   -> issue stage(kt+1) -> 48 MFMA. Staging now has a full MFMA block
//   (~700 cyc/SIMD) to drain before the next barrier A -> ~0 exposed latency.
//   Race-safe: __syncthreads drains lgkm before s_barrier, so all reads of
//   buf retired before any wave overwrites it.
// MODE 1 (BN=96, out-proj): proven double-buffered loop, 2/CU resident.
// T2 swizzle: granule g' = g ^ (row&7), inverse-swizzled source.
// ---------------------------------------------------------------------------
template <int BN, int MODE>
__global__ __launch_bounds__(256, (MODE == 0) ? 3 : 2) void gemm_tile(
    const unsigned short* __restrict__ A, const unsigned short* __restrict__ Wt,
    const float* __restrict__ b0, const float* __restrict__ b1,
    const float* __restrict__ b2,
    unsigned short* __restrict__ qg, unsigned short* __restrict__ kg,
    unsigned short* __restrict__ vtg, float* __restrict__ outF)
{
    constexpr int NFC = BN / 32;                 // per-wave n-frags
    constexpr int NY = (MODE == 0 ? 2304 : 768) / BN;
    constexpr int NBUF = (MODE == 0) ? 1 : 2;
    __shared__ __align__(16) unsigned short As[NBUF][128 * 64];
    __shared__ __align__(16) unsigned short Bs[NBUF][BN * 64];

    const int tid = threadIdx.x;
    const int lane = tid & 63, w = tid >> 6;     // 4 waves
    const int L15 = lane & 15, quad = lane >> 4;
    const int wm = w >> 1, wn = w & 1;           // wave grid 2M x 2N

    const int raw = blockIdx.x;
    const int xcd = raw & 7, i = raw >> 3;
    const int mx = xcd * 8 + i / NY;             // 0..63
    const int ny = i % NY;

    const int lr = lane >> 3;                    // 0..7
    const int lg8 = (lane & 7) ^ lr;             // swizzled 8-elem k-granule
    const size_t aBase = (size_t)(mx * 128 + w * 8 + lr) * C_DIM + lg8 * 8;
    const size_t bBase = (size_t)(ny * BN + w * 8 + lr) * C_DIM + lg8 * 8;

    auto stage = [&](int kt, int buf) {
        const size_t ko = (size_t)kt * 64;
#pragma unroll
        for (int c = 0; c < 4; c++)
            gl2lds16(&A[aBase + (size_t)c * 32 * C_DIM + ko],
                     &As[buf][(c * 32 + w * 8) * 64]);
#pragma unroll
        for (int c = 0; c < BN / 32; c++)
            gl2lds16(&Wt[bBase + (size_t)c * 32 * C_DIM + ko],
                     &Bs[buf][(c * 32 + w * 8) * 64]);
    };

    const int sg0 = (quad ^ (L15 & 7)) * 16;
    const int sg1 = ((4 + quad) ^ (L15 & 7)) * 16;
    const int aRowB = (wm * 64 + L15) * 128;
    const int bRowB = (wn * (BN / 2) + L15) * 128;

    f32x4 acc[4][NFC];
#pragma unroll
    for (int fr = 0; fr < 4; fr++)
#pragma unroll
        for (int fc = 0; fc < NFC; fc++) acc[fr][fc] = 0.0f;

    stage(0, 0);

    if (MODE == 0) {
        // single-buffer, stage-early loop (see header comment)
        for (int kt = 0; kt < 12; kt++) {
            __syncthreads();                     // A: staging vmcnt drained; buf ready
            const char* Ac = (const char*)As[0];
            const char* Bc = (const char*)Bs[0];
            bf16x8 av[4][2], bv[NFC][2];
#pragma unroll
            for (int fr = 0; fr < 4; fr++)
#pragma unroll
                for (int kh = 0; kh < 2; kh++)
                    av[fr][kh] = *(const bf16x8*)(Ac + aRowB + fr * 2048 + (kh ? sg1 : sg0));
#pragma unroll
            for (int fc = 0; fc < NFC; fc++)
#pragma unroll
                for (int kh = 0; kh < 2; kh++)
                    bv[fc][kh] = *(const bf16x8*)(Bc + bRowB + fc * 2048 + (kh ? sg1 : sg0));
            if (kt < 11) {
                __syncthreads();                 // B: all waves' reads retired
                stage(kt + 1, 0);                // overwrite; drains under MFMA below
            }
            __builtin_amdgcn_s_setprio(1);
#pragma unroll
            for (int fr = 0; fr < 4; fr++)
#pragma unroll
                for (int fc = 0; fc < NFC; fc++)
#pragma unroll
                    for (int kh = 0; kh < 2; kh++)
                        acc[fr][fc] = __builtin_amdgcn_mfma_f32_16x16x32_bf16(
                            av[fr][kh], bv[fc][kh], acc[fr][fc], 0, 0, 0);
            __builtin_amdgcn_s_setprio(0);
        }
    } else {
        // proven double-buffered loop (one barrier per K-iter)
        __syncthreads();
        for (int kt = 0; kt < 12; kt++) {
            const int cur = kt & 1;
            if (kt < 11) stage(kt + 1, cur ^ 1);
            const char* Ac = (const char*)As[cur & (NBUF - 1)];
            const char* Bc = (const char*)Bs[cur & (NBUF - 1)];
            bf16x8 av[4][2], bv[NFC][2];
#pragma unroll
            for (int fr = 0; fr < 4; fr++)
#pragma unroll
                for (int kh = 0; kh < 2; kh++)
                    av[fr][kh] = *(const bf16x8*)(Ac + aRowB + fr * 2048 + (kh ? sg1 : sg0));
#pragma unroll
            for (int fc = 0; fc < NFC; fc++)
#pragma unroll
                for (int kh = 0; kh < 2; kh++)
                    bv[fc][kh] = *(const bf16x8*)(Bc + bRowB + fc * 2048 + (kh ? sg1 : sg0));
            __builtin_amdgcn_s_setprio(1);
#pragma unroll
            for (int fr = 0; fr < 4; fr++)
#pragma unroll
                for (int fc = 0; fc < NFC; fc++)
#pragma unroll
                    for (int kh = 0; kh < 2; kh++)
                        acc[fr][fc] = __builtin_amdgcn_mfma_f32_16x16x32_bf16(
                            av[fr][kh], bv[fc][kh], acc[fr][fc], 0, 0, 0);
            __builtin_amdgcn_s_setprio(0);
            __syncthreads();
        }
    }

    if (MODE == 0) {
        const int z = (ny * BN) / 768;           // uniform per block
        const float* bias = (z == 0) ? b0 : (z == 1) ? b1 : b2;
        const float qs = (z == 0) ? 0.18033688011112042f : 1.0f;  // 0.125/ln2
#pragma unroll
        for (int fc = 0; fc < NFC; fc++) {
            const int n = ny * BN + wn * (BN / 2) + fc * 16 + L15;
            const int nl = n - z * 768;
            const int h = nl >> 6, d = nl & 63;
            const float bn = bias[nl];
#pragma unroll
            for (int fr = 0; fr < 4; fr++) {
                const int mB = mx * 128 + wm * 64 + fr * 16 + quad * 4;
                const int b = mB >> 11, tB = mB & (T_LEN - 1);
                if (z < 2) {
                    unsigned short* o = z ? kg : qg;
#pragma unroll
                    for (int r = 0; r < 4; r++)
                        o[(((size_t)(b * NH + h)) * T_LEN + tB + r) * HD + d] =
                            f2bf((acc[fr][fc][r] + bn) * qs);
                } else {
                    ushort4 o4;
                    o4.x = f2bf(acc[fr][fc][0] + bn);
                    o4.y = f2bf(acc[fr][fc][1] + bn);
                    o4.z = f2bf(acc[fr][fc][2] + bn);
                    o4.w = f2bf(acc[fr][fc][3] + bn);
                    *(ushort4*)&vtg[(((size_t)(b * NH + h)) * HD + d) * T_LEN + tB] = o4;
                }
            }
        }
    } else {
#pragma unroll
        for (int fc = 0; fc < NFC; fc++) {
            const int n = ny * BN + wn * (BN / 2) + fc * 16 + L15;
            const float bn = b0[n];
#pragma unroll
            for (int fr = 0; fr < 4; fr++) {
                const int mB = mx * 128 + wm * 64 + fr * 16 + quad * 4;
#pragma unroll
                for (int r = 0; r < 4; r++)
                    outF[(size_t)(mB + r) * C_DIM + n] = acc[fr][fc][r] + bn;
            }
        }
    }
}

// ---------------------------------------------------------------------------
// MFMA flash attention with kt-window (causal flash-decoding), 24-unit LUT.
// PROVEN round-20 version (202.31us): CH=512, launch_bounds (256,4).
// ---------------------------------------------------------------------------
__global__ __launch_bounds__(256, 4) void attn_part(
    const unsigned short* __restrict__ qg, const unsigned short* __restrict__ kg,
    const unsigned short* __restrict__ vtg, unsigned short* __restrict__ attb,
    float* __restrict__ pO, float* __restrict__ pL)
{
    // unit LUT: (qs, k0, k1), size-descending for LPT packing
    static const unsigned char Uqs[24] = {15,15,7,14,14,6,13,13,12,12,5,11,
                                          11,10,10,4,9,9,8,8,3,2,1,0};
    static const unsigned char Uk0[24] = {0,16,0,0,15,0,0,14,0,13,0,0,
                                          12,0,11,0,0,10,0,9,0,0,0,0};
    static const unsigned char Uk1[24] = {16,32,16,15,30,14,14,28,13,26,12,12,
                                          24,11,22,10,10,20,9,18,8,6,4,2};

    __shared__ __align__(16) unsigned short Ks[2][8 * CH];
    __shared__ __align__(16) unsigned short Vs[2][8 * CH];
    const int tid = threadIdx.x;
    const int lane = tid & 63, w = tid >> 6;
    const int L15 = lane & 15, L31 = lane & 31;
    const int quad = lane >> 4, r4 = (lane >> 4) & 1, r5 = lane >> 5;

    const int n = blockIdx.x;
    const int bh = n % (B_SZ * NH);              // consecutive -> XCD RR, 6 bh/XCD
    const int u = n / (B_SZ * NH);               // 0..23
    const int qs = Uqs[u];
    const int k0 = Uk0[u], k1 = Uk1[u];
    const size_t base = (size_t)bh * T_LEN * HD;
    const int q0 = qs * 128;
    const int qrow = q0 + w * 32 + L31;

    bf16x8 qf[4];
#pragma unroll
    for (int kc = 0; kc < 4; kc++)
        qf[kc] = *(const bf16x8*)&qg[base + (size_t)qrow * HD + kc * 16 + r5 * 8];

    f32x16 accO[2];
#pragma unroll
    for (int md = 0; md < 2; md++) accO[md] = 0.0f;
    f32x4 lacc = 0.0f;

    auto stage = [&](int kt, int buf) {
        const int ktb = kt * 64;
        gl2lds16(&kg[base + (size_t)(ktb + w * 16 + L15) * HD + quad * 8],
                 &Ks[buf][(2 * w) * CH]);
        gl2lds16(&kg[base + (size_t)(ktb + w * 16 + L15) * HD + 32 + quad * 8],
                 &Ks[buf][(2 * w + 1) * CH]);
        gl2lds16(&vtg[base + (size_t)(w * 16 + L15) * T_LEN + ktb + quad * 8],
                 &Vs[buf][(2 * w) * CH]);
        gl2lds16(&vtg[base + (size_t)(w * 16 + L15) * T_LEN + ktb + 32 + quad * 8],
                 &Vs[buf][(2 * w + 1) * CH]);
    };

    stage(k0, 0);
    __syncthreads();

    const int qmaxw = q0 + w * 32 + 31;
    const int qminw = q0 + w * 32;

    for (int kt = k0; kt < k1; kt++) {
        const int cur = (kt - k0) & 1;
        if (kt + 1 < k1) stage(kt + 1, cur ^ 1);
        const int ktb = kt * 64;
        if (ktb <= qmaxw) {
            f32x16 sa[2];
#pragma unroll
            for (int mi = 0; mi < 2; mi++) {
                sa[mi] = 0.0f;
#pragma unroll
                for (int kc = 0; kc < 4; kc++) {
                    const int ck = mi * 4 + r4 * 2 + (kc >> 1);
                    const int slot = L15 + 16 * ((kc & 1) * 2 + r5);
                    bf16x8 kf = *(const bf16x8*)&Ks[cur][ck * CH + slot * 8];
                    sa[mi] = __builtin_amdgcn_mfma_f32_32x32x16_bf16(
                        kf, qf[kc], sa[mi], 0, 0, 0);
                }
            }
            const bool needmask = (ktb + 63 > qminw);
            bf16x8 pfrag[4];
#pragma unroll
            for (int mi = 0; mi < 2; mi++) {
                float e[16];
#pragma unroll
                for (int g = 0; g < 4; g++) {
#pragma unroll
                    for (int rr = 0; rr < 4; rr++) {
                        float s = sa[mi][g * 4 + rr];
                        if (needmask) {
                            const int key = ktb + mi * 32 + 8 * g + 4 * r5 + rr;
                            s = (key <= qrow) ? s : -1e30f;
                        }
                        e[g * 4 + rr] = fast_exp2(s);
                        lacc[rr] += e[g * 4 + rr];
                    }
                }
#pragma unroll
                for (int h = 0; h < 2; h++) {
                    unsigned a0 = cvt_pk_bf16(e[8 * h + 0], e[8 * h + 1]);
                    unsigned a1 = cvt_pk_bf16(e[8 * h + 2], e[8 * h + 3]);
                    unsigned b0 = cvt_pk_bf16(e[8 * h + 4], e[8 * h + 5]);
                    unsigned b1 = cvt_pk_bf16(e[8 * h + 6], e[8 * h + 7]);
                    perml32_swap(a0, b0);
                    perml32_swap(a1, b1);
                    union { unsigned u[4]; bf16x8 v; } pf;
                    pf.u[0] = a0; pf.u[1] = a1; pf.u[2] = b0; pf.u[3] = b1;
                    pfrag[2 * mi + h] = pf.v;
                }
            }
#pragma unroll
            for (int md = 0; md < 2; md++) {
#pragma unroll
                for (int kc = 0; kc < 4; kc++) {
                    const int cv = md * 4 + r4 * 2 + (kc >> 1);
                    const int slot = L15 + 16 * ((kc & 1) * 2 + r5);
                    bf16x8 vf = *(const bf16x8*)&Vs[cur][cv * CH + slot * 8];
                    accO[md] = __builtin_amdgcn_mfma_f32_32x32x16_bf16(
                        vf, pfrag[kc], accO[md], 0, 0, 0);
                }
            }
        }
        __syncthreads();
    }

    const float l = (lacc[0] + lacc[1]) + (lacc[2] + lacc[3]);
    const bool split = (k0 != 0) || (k1 != 2 * qs + 2);
    if (!split) {
        const float lt = l + __shfl_xor(l, 32, 64);
        const float inv = __builtin_amdgcn_rcpf(lt);
        const int b = bh / NH, h = bh % NH;
        const size_t orow = ((size_t)(b * T_LEN + qrow)) * C_DIM + h * HD;
#pragma unroll
        for (int md = 0; md < 2; md++) {
#pragma unroll
            for (int g = 0; g < 4; g++) {
                uint2 wv;
                wv.x = (unsigned)f2bf(accO[md][g * 4 + 0] * inv) |
                       ((unsigned)f2bf(accO[md][g * 4 + 1] * inv) << 16);
                wv.y = (unsigned)f2bf(accO[md][g * 4 + 2] * inv) |
                       ((unsigned)f2bf(accO[md][g * 4 + 3] * inv) << 16);
                *(uint2*)&attb[orow + md * 32 + 8 * g + 4 * r5] = wv;
            }
        }
    } else {
        const int strip = bh * 8 + (qs - 8);
        const int seg = (k0 != 0) ? 1 : 0;
        float4* pO4 = (float4*)pO;
        const size_t pbase = ((size_t)(strip * 2 + seg) * 4 + w) * 512 + lane;
#pragma unroll
        for (int md = 0; md < 2; md++)
#pragma unroll
            for (int g = 0; g < 4; g++) {
                float4 v4;
                v4.x = accO[md][g * 4 + 0];
                v4.y = accO[md][g * 4 + 1];
                v4.z = accO[md][g * 4 + 2];
                v4.w = accO[md][g * 4 + 3];
                pO4[pbase + (size_t)(md * 4 + g) * 64] = v4;
            }
        pL[(size_t)(strip * 2 + seg) * 256 + w * 64 + lane] = l;
    }
}

// ---------------------------------------------------------------------------
// Combine the two kt-segments of each heavy q-strip: O=(O1+O2)/(l1+l2).
// grid 384 x 256: thread = (strip 0..383, w 0..3, lane 0..63).
// ---------------------------------------------------------------------------
__global__ __launch_bounds__(256) void attn_comb(
    const float* __restrict__ pO, const float* __restrict__ pL,
    unsigned short* __restrict__ attb)
{
    const int g = blockIdx.x * 256 + threadIdx.x;
    const int lane = g & 63, w = (g >> 6) & 3, strip = g >> 8;  // 0..383
    const int r5 = lane >> 5, L31 = lane & 31;
    const int bh = strip >> 3, qs = 8 + (strip & 7);

    const float4* pO4 = (const float4*)pO;
    const size_t b0 = ((size_t)(strip * 2 + 0) * 4 + w) * 512 + lane;
    const size_t b1 = ((size_t)(strip * 2 + 1) * 4 + w) * 512 + lane;
    const float l = pL[(size_t)(strip * 2 + 0) * 256 + w * 64 + lane] +
                    pL[(size_t)(strip * 2 + 1) * 256 + w * 64 + lane];
    const float lt = l + __shfl_xor(l, 32, 64);
    const float inv = __builtin_amdgcn_rcpf(lt);

    const int qrow = qs * 128 + w * 32 + L31;
    const int b = bh / NH, h = bh % NH;
    const size_t orow = ((size_t)(b * T_LEN + qrow)) * C_DIM + h * HD;
#pragma unroll
    for (int md = 0; md < 2; md++)
#pragma unroll
        for (int gq = 0; gq < 4; gq++) {
            const size_t e = (size_t)(md * 4 + gq) * 64;
            float4 v1 = pO4[b0 + e];
            float4 v2 = pO4[b1 + e];
            uint2 wv;
            wv.x = (unsigned)f2bf((v1.x + v2.x) * inv) |
                   ((unsigned)f2bf((v1.y + v2.y) * inv) << 16);
            wv.y = (unsigned)f2bf((v1.z + v2.z) * inv) |
                   ((unsigned)f2bf((v1.w + v2.w) * inv) << 16);
            *(uint2*)&attb[orow + md * 32 + 8 * gq + 4 * r5] = wv;
        }
}

extern "C" void kernel_launch(void* const* d_in, const int* in_sizes, int n_in,
                              void* d_out, int out_size, void* d_ws, size_t ws_size,
                              hipStream_t stream)
{
    const float* x  = (const float*)d_in[0];
    const float* Wq = (const float*)d_in[1];
    const float* bq = (const float*)d_in[2];
    const float* Wk = (const float*)d_in[3];
    const float* bk = (const float*)d_in[4];
    const float* Wv = (const float*)d_in[5];
    const float* bv = (const float*)d_in[6];
    const float* Wo = (const float*)d_in[7];
    const float* bo = (const float*)d_in[8];
    float* out = (float*)d_out;

    const size_t nMC = (size_t)M_ROWS * C_DIM;  // 6291456
    unsigned short* xb   = (unsigned short*)d_ws;
    unsigned short* Wt   = xb + nMC;
    unsigned short* qg   = Wt + 4 * (size_t)WSZ;
    unsigned short* kg   = qg + nMC;
    unsigned short* vtg  = kg + nMC;
    unsigned short* attb = vtg + nMC;
    // scratch reuse: pO = d_out (25.2MB, overwritten by final GEMM);
    // pL lives in the dead xb region (xb unused after gemm_qkv).
    float* pO = out;
    float* pL = (float*)xb;

    conv_x<<<(int)(nMC / 1024), 256, 0, stream>>>(x, xb);
    conv_wt<<<dim3(24, 24, 4), 256, 0, stream>>>(Wq, Wk, Wv, Wo, Wt);
    gemm_tile<192, 0><<<768, 256, 0, stream>>>(xb, Wt, bq, bk, bv,
                                               qg, kg, vtg, nullptr);
    attn_part<<<24 * B_SZ * NH, 256, 0, stream>>>(qg, kg, vtg, attb, pO, pL);
    attn_comb<<<384, 256, 0, stream>>>(pO, pL, attb);
    gemm_tile<96, 1><<<512, 256, 0, stream>>>(attb, Wt + 3 * (size_t)WSZ,
                                              bo, bo, bo, nullptr, nullptr,
                                              nullptr, out);
}

// Round 22
// 201.069 us; speedup vs baseline: 1.2585x; 1.2585x over previous
//
#include <hip/hip_runtime.h>

#define T_LEN 2048
#define C_DIM 768
#define NH 12
#define HD 64
#define B_SZ 4
#define M_ROWS (B_SZ * T_LEN)  // 8192
#define WSZ (C_DIM * C_DIM)    // 589824
#define CH 512                 // attn LDS chunk stride: 1024B exact -> 32KB LDS, 0 bank conflicts

typedef __bf16 bf16x8 __attribute__((ext_vector_type(8)));
typedef float f32x4 __attribute__((ext_vector_type(4)));
typedef float f32x16 __attribute__((ext_vector_type(16)));

__device__ __forceinline__ unsigned short f2bf(float f) {
    union { __bf16 b; unsigned short u; } c;
    c.b = (__bf16)f;
    return c.u;
}

__device__ __forceinline__ float fast_exp2(float x) {
    float r;
    asm("v_exp_f32 %0, %1" : "=v"(r) : "v"(x));
    return r;
}

// pack two f32 -> one u32 of 2x bf16 (lo=a, hi=b)
__device__ __forceinline__ unsigned cvt_pk_bf16(float a, float b) {
    unsigned r;
    asm("v_cvt_pk_bf16_f32 %0, %1, %2" : "=v"(r) : "v"(a), "v"(b));
    return r;
}

// exchange a[lanes 32..63] with b[lanes 0..31]
__device__ __forceinline__ void perml32_swap(unsigned& a, unsigned& b) {
    asm("v_permlane32_swap_b32 %0, %1" : "+v"(a), "+v"(b));
}

// async global->LDS, 16B/lane; LDS dest = uniform base + lane*16.
__device__ __forceinline__ void gl2lds16(const void* g, void* l) {
    __builtin_amdgcn_global_load_lds(
        (const __attribute__((address_space(1))) unsigned int*)g,
        (__attribute__((address_space(3))) unsigned int*)l, 16, 0, 0);
}

// ---------------------------------------------------------------------------
// x [8192][768] fp32 -> bf16 row-major
// ---------------------------------------------------------------------------
__global__ __launch_bounds__(256) void conv_x(const float* __restrict__ x,
                                              unsigned short* __restrict__ xb)
{
    const int i = blockIdx.x * 256 + threadIdx.x;
    float4 v = ((const float4*)x)[i];
    ushort4 o;
    o.x = f2bf(v.x); o.y = f2bf(v.y); o.z = f2bf(v.z); o.w = f2bf(v.w);
    ((ushort4*)xb)[i] = o;
}

// ---------------------------------------------------------------------------
// W [768][768] fp32 (k-major) -> Wt [768][768] bf16 (n-major, i.e. W^T)
// ---------------------------------------------------------------------------
__global__ __launch_bounds__(256) void conv_wt(
    const float* __restrict__ W0, const float* __restrict__ W1,
    const float* __restrict__ W2, const float* __restrict__ W3,
    unsigned short* __restrict__ WtAll)
{
    __shared__ float tile[32][33];
    const int z = blockIdx.z;
    const float* W = (z == 0) ? W0 : (z == 1) ? W1 : (z == 2) ? W2 : W3;
    unsigned short* out = WtAll + (size_t)z * WSZ;
    const int k0 = blockIdx.x * 32, n0 = blockIdx.y * 32;
    const int r = threadIdx.x >> 3, c4 = (threadIdx.x & 7) * 4;
    float4 v = *(const float4*)&W[(size_t)(k0 + r) * C_DIM + n0 + c4];
    tile[r][c4 + 0] = v.x;
    tile[r][c4 + 1] = v.y;
    tile[r][c4 + 2] = v.z;
    tile[r][c4 + 3] = v.w;
    __syncthreads();
    ushort4 o;
    o.x = f2bf(tile[c4 + 0][r]);
    o.y = f2bf(tile[c4 + 1][r]);
    o.z = f2bf(tile[c4 + 2][r]);
    o.w = f2bf(tile[c4 + 3][r]);
    *(ushort4*)&out[(size_t)(n0 + r) * C_DIM + k0 + c4] = o;
}

// ---------------------------------------------------------------------------
// Tiled bf16 MFMA GEMM, tile 128xBN, BK=64, 4 waves (2x2).
// MODE 0 (BN=192, fused QKV): SINGLE-buffered LDS (40KB) + 2-barrier K-loop,
//   per-kh fragment loads (low liveness -- holding all frags across a barrier
//   spills, round-21 lesson). 3 blocks/CU all resident (grid 768 = 3/CU).
// MODE 1 (BN=96, out-proj): proven double-buffered loop, 2/CU resident.
// T2 swizzle: granule g' = g ^ (row&7), inverse-swizzled source.
// ---------------------------------------------------------------------------
template <int BN, int MODE>
__global__ __launch_bounds__(256, (MODE == 0) ? 3 : 2) void gemm_tile(
    const unsigned short* __restrict__ A, const unsigned short* __restrict__ Wt,
    const float* __restrict__ b0, const float* __restrict__ b1,
    const float* __restrict__ b2,
    unsigned short* __restrict__ qg, unsigned short* __restrict__ kg,
    unsigned short* __restrict__ vtg, float* __restrict__ outF)
{
    constexpr int NFC = BN / 32;                 // per-wave n-frags
    constexpr int NY = (MODE == 0 ? 2304 : 768) / BN;
    constexpr int NBUF = (MODE == 0) ? 1 : 2;
    __shared__ __align__(16) unsigned short As[NBUF][128 * 64];
    __shared__ __align__(16) unsigned short Bs[NBUF][BN * 64];

    const int tid = threadIdx.x;
    const int lane = tid & 63, w = tid >> 6;     // 4 waves
    const int L15 = lane & 15, quad = lane >> 4;
    const int wm = w >> 1, wn = w & 1;           // wave grid 2M x 2N

    const int raw = blockIdx.x;
    const int xcd = raw & 7, i = raw >> 3;
    const int mx = xcd * 8 + i / NY;             // 0..63
    const int ny = i % NY;

    const int lr = lane >> 3;                    // 0..7
    const int lg8 = (lane & 7) ^ lr;             // swizzled 8-elem k-granule
    const size_t aBase = (size_t)(mx * 128 + w * 8 + lr) * C_DIM + lg8 * 8;
    const size_t bBase = (size_t)(ny * BN + w * 8 + lr) * C_DIM + lg8 * 8;

    auto stage = [&](int kt, int buf) {
        const size_t ko = (size_t)kt * 64;
#pragma unroll
        for (int c = 0; c < 4; c++)
            gl2lds16(&A[aBase + (size_t)c * 32 * C_DIM + ko],
                     &As[buf][(c * 32 + w * 8) * 64]);
#pragma unroll
        for (int c = 0; c < BN / 32; c++)
            gl2lds16(&Wt[bBase + (size_t)c * 32 * C_DIM + ko],
                     &Bs[buf][(c * 32 + w * 8) * 64]);
    };

    const int sg0 = (quad ^ (L15 & 7)) * 16;
    const int sg1 = ((4 + quad) ^ (L15 & 7)) * 16;
    const int aRowB = (wm * 64 + L15) * 128;
    const int bRowB = (wn * (BN / 2) + L15) * 128;

    f32x4 acc[4][NFC];
#pragma unroll
    for (int fr = 0; fr < 4; fr++)
#pragma unroll
        for (int fc = 0; fc < NFC; fc++) acc[fr][fc] = 0.0f;

    stage(0, 0);

    if (MODE == 0) {
        // single-buffer 2-barrier loop; 3 co-resident blocks hide the drain
        for (int kt = 0; kt < 12; kt++) {
            __syncthreads();                     // drains staging vmcnt; data ready
            const char* Ac = (const char*)As[0];
            const char* Bc = (const char*)Bs[0];
#pragma unroll
            for (int kh = 0; kh < 2; kh++) {     // per-kh: low frag liveness
                bf16x8 av[4], bv[NFC];
#pragma unroll
                for (int fr = 0; fr < 4; fr++)
                    av[fr] = *(const bf16x8*)(Ac + aRowB + fr * 2048 + (kh ? sg1 : sg0));
#pragma unroll
                for (int fc = 0; fc < NFC; fc++)
                    bv[fc] = *(const bf16x8*)(Bc + bRowB + fc * 2048 + (kh ? sg1 : sg0));
                __builtin_amdgcn_s_setprio(1);
#pragma unroll
                for (int fr = 0; fr < 4; fr++)
#pragma unroll
                    for (int fc = 0; fc < NFC; fc++)
                        acc[fr][fc] = __builtin_amdgcn_mfma_f32_16x16x32_bf16(
                            av[fr], bv[fc], acc[fr][fc], 0, 0, 0);
                __builtin_amdgcn_s_setprio(0);
            }
            if (kt < 11) {
                __syncthreads();                 // all waves done reading buf
                stage(kt + 1, 0);
            }
        }
    } else {
        // proven double-buffered loop (one barrier per K-iter)
        __syncthreads();
        for (int kt = 0; kt < 12; kt++) {
            const int cur = kt & 1;
            if (kt < 11) stage(kt + 1, cur ^ 1);
            const char* Ac = (const char*)As[cur & (NBUF - 1)];
            const char* Bc = (const char*)Bs[cur & (NBUF - 1)];
            bf16x8 av[4][2], bv[NFC][2];
#pragma unroll
            for (int fr = 0; fr < 4; fr++)
#pragma unroll
                for (int kh = 0; kh < 2; kh++)
                    av[fr][kh] = *(const bf16x8*)(Ac + aRowB + fr * 2048 + (kh ? sg1 : sg0));
#pragma unroll
            for (int fc = 0; fc < NFC; fc++)
#pragma unroll
                for (int kh = 0; kh < 2; kh++)
                    bv[fc][kh] = *(const bf16x8*)(Bc + bRowB + fc * 2048 + (kh ? sg1 : sg0));
            __builtin_amdgcn_s_setprio(1);
#pragma unroll
            for (int fr = 0; fr < 4; fr++)
#pragma unroll
                for (int fc = 0; fc < NFC; fc++)
#pragma unroll
                    for (int kh = 0; kh < 2; kh++)
                        acc[fr][fc] = __builtin_amdgcn_mfma_f32_16x16x32_bf16(
                            av[fr][kh], bv[fc][kh], acc[fr][fc], 0, 0, 0);
            __builtin_amdgcn_s_setprio(0);
            __syncthreads();
        }
    }

    if (MODE == 0) {
        const int z = (ny * BN) / 768;           // uniform per block
        const float* bias = (z == 0) ? b0 : (z == 1) ? b1 : b2;
        const float qs = (z == 0) ? 0.18033688011112042f : 1.0f;  // 0.125/ln2
#pragma unroll
        for (int fc = 0; fc < NFC; fc++) {
            const int n = ny * BN + wn * (BN / 2) + fc * 16 + L15;
            const int nl = n - z * 768;
            const int h = nl >> 6, d = nl & 63;
            const float bn = bias[nl];
#pragma unroll
            for (int fr = 0; fr < 4; fr++) {
                const int mB = mx * 128 + wm * 64 + fr * 16 + quad * 4;
                const int b = mB >> 11, tB = mB & (T_LEN - 1);
                if (z < 2) {
                    unsigned short* o = z ? kg : qg;
#pragma unroll
                    for (int r = 0; r < 4; r++)
                        o[(((size_t)(b * NH + h)) * T_LEN + tB + r) * HD + d] =
                            f2bf((acc[fr][fc][r] + bn) * qs);
                } else {
                    ushort4 o4;
                    o4.x = f2bf(acc[fr][fc][0] + bn);
                    o4.y = f2bf(acc[fr][fc][1] + bn);
                    o4.z = f2bf(acc[fr][fc][2] + bn);
                    o4.w = f2bf(acc[fr][fc][3] + bn);
                    *(ushort4*)&vtg[(((size_t)(b * NH + h)) * HD + d) * T_LEN + tB] = o4;
                }
            }
        }
    } else {
#pragma unroll
        for (int fc = 0; fc < NFC; fc++) {
            const int n = ny * BN + wn * (BN / 2) + fc * 16 + L15;
            const float bn = b0[n];
#pragma unroll
            for (int fr = 0; fr < 4; fr++) {
                const int mB = mx * 128 + wm * 64 + fr * 16 + quad * 4;
#pragma unroll
                for (int r = 0; r < 4; r++)
                    outF[(size_t)(mB + r) * C_DIM + n] = acc[fr][fc][r] + bn;
            }
        }
    }
}

// ---------------------------------------------------------------------------
// MFMA flash attention with kt-window (causal flash-decoding), 24-unit LUT.
// PROVEN round-20 version (202.31us): CH=512, launch_bounds (256,4).
// ---------------------------------------------------------------------------
__global__ __launch_bounds__(256, 4) void attn_part(
    const unsigned short* __restrict__ qg, const unsigned short* __restrict__ kg,
    const unsigned short* __restrict__ vtg, unsigned short* __restrict__ attb,
    float* __restrict__ pO, float* __restrict__ pL)
{
    // unit LUT: (qs, k0, k1), size-descending for LPT packing
    static const unsigned char Uqs[24] = {15,15,7,14,14,6,13,13,12,12,5,11,
                                          11,10,10,4,9,9,8,8,3,2,1,0};
    static const unsigned char Uk0[24] = {0,16,0,0,15,0,0,14,0,13,0,0,
                                          12,0,11,0,0,10,0,9,0,0,0,0};
    static const unsigned char Uk1[24] = {16,32,16,15,30,14,14,28,13,26,12,12,
                                          24,11,22,10,10,20,9,18,8,6,4,2};

    __shared__ __align__(16) unsigned short Ks[2][8 * CH];
    __shared__ __align__(16) unsigned short Vs[2][8 * CH];
    const int tid = threadIdx.x;
    const int lane = tid & 63, w = tid >> 6;
    const int L15 = lane & 15, L31 = lane & 31;
    const int quad = lane >> 4, r4 = (lane >> 4) & 1, r5 = lane >> 5;

    const int n = blockIdx.x;
    const int bh = n % (B_SZ * NH);              // consecutive -> XCD RR, 6 bh/XCD
    const int u = n / (B_SZ * NH);               // 0..23
    const int qs = Uqs[u];
    const int k0 = Uk0[u], k1 = Uk1[u];
    const size_t base = (size_t)bh * T_LEN * HD;
    const int q0 = qs * 128;
    const int qrow = q0 + w * 32 + L31;

    bf16x8 qf[4];
#pragma unroll
    for (int kc = 0; kc < 4; kc++)
        qf[kc] = *(const bf16x8*)&qg[base + (size_t)qrow * HD + kc * 16 + r5 * 8];

    f32x16 accO[2];
#pragma unroll
    for (int md = 0; md < 2; md++) accO[md] = 0.0f;
    f32x4 lacc = 0.0f;

    auto stage = [&](int kt, int buf) {
        const int ktb = kt * 64;
        gl2lds16(&kg[base + (size_t)(ktb + w * 16 + L15) * HD + quad * 8],
                 &Ks[buf][(2 * w) * CH]);
        gl2lds16(&kg[base + (size_t)(ktb + w * 16 + L15) * HD + 32 + quad * 8],
                 &Ks[buf][(2 * w + 1) * CH]);
        gl2lds16(&vtg[base + (size_t)(w * 16 + L15) * T_LEN + ktb + quad * 8],
                 &Vs[buf][(2 * w) * CH]);
        gl2lds16(&vtg[base + (size_t)(w * 16 + L15) * T_LEN + ktb + 32 + quad * 8],
                 &Vs[buf][(2 * w + 1) * CH]);
    };

    stage(k0, 0);
    __syncthreads();

    const int qmaxw = q0 + w * 32 + 31;
    const int qminw = q0 + w * 32;

    for (int kt = k0; kt < k1; kt++) {
        const int cur = (kt - k0) & 1;
        if (kt + 1 < k1) stage(kt + 1, cur ^ 1);
        const int ktb = kt * 64;
        if (ktb <= qmaxw) {
            f32x16 sa[2];
#pragma unroll
            for (int mi = 0; mi < 2; mi++) {
                sa[mi] = 0.0f;
#pragma unroll
                for (int kc = 0; kc < 4; kc++) {
                    const int ck = mi * 4 + r4 * 2 + (kc >> 1);
                    const int slot = L15 + 16 * ((kc & 1) * 2 + r5);
                    bf16x8 kf = *(const bf16x8*)&Ks[cur][ck * CH + slot * 8];
                    sa[mi] = __builtin_amdgcn_mfma_f32_32x32x16_bf16(
                        kf, qf[kc], sa[mi], 0, 0, 0);
                }
            }
            const bool needmask = (ktb + 63 > qminw);
            bf16x8 pfrag[4];
#pragma unroll
            for (int mi = 0; mi < 2; mi++) {
                float e[16];
#pragma unroll
                for (int g = 0; g < 4; g++) {
#pragma unroll
                    for (int rr = 0; rr < 4; rr++) {
                        float s = sa[mi][g * 4 + rr];
                        if (needmask) {
                            const int key = ktb + mi * 32 + 8 * g + 4 * r5 + rr;
                            s = (key <= qrow) ? s : -1e30f;
                        }
                        e[g * 4 + rr] = fast_exp2(s);
                        lacc[rr] += e[g * 4 + rr];
                    }
                }
#pragma unroll
                for (int h = 0; h < 2; h++) {
                    unsigned a0 = cvt_pk_bf16(e[8 * h + 0], e[8 * h + 1]);
                    unsigned a1 = cvt_pk_bf16(e[8 * h + 2], e[8 * h + 3]);
                    unsigned b0 = cvt_pk_bf16(e[8 * h + 4], e[8 * h + 5]);
                    unsigned b1 = cvt_pk_bf16(e[8 * h + 6], e[8 * h + 7]);
                    perml32_swap(a0, b0);
                    perml32_swap(a1, b1);
                    union { unsigned u[4]; bf16x8 v; } pf;
                    pf.u[0] = a0; pf.u[1] = a1; pf.u[2] = b0; pf.u[3] = b1;
                    pfrag[2 * mi + h] = pf.v;
                }
            }
#pragma unroll
            for (int md = 0; md < 2; md++) {
#pragma unroll
                for (int kc = 0; kc < 4; kc++) {
                    const int cv = md * 4 + r4 * 2 + (kc >> 1);
                    const int slot = L15 + 16 * ((kc & 1) * 2 + r5);
                    bf16x8 vf = *(const bf16x8*)&Vs[cur][cv * CH + slot * 8];
                    accO[md] = __builtin_amdgcn_mfma_f32_32x32x16_bf16(
                        vf, pfrag[kc], accO[md], 0, 0, 0);
                }
            }
        }
        __syncthreads();
    }

    const float l = (lacc[0] + lacc[1]) + (lacc[2] + lacc[3]);
    const bool split = (k0 != 0) || (k1 != 2 * qs + 2);
    if (!split) {
        const float lt = l + __shfl_xor(l, 32, 64);
        const float inv = __builtin_amdgcn_rcpf(lt);
        const int b = bh / NH, h = bh % NH;
        const size_t orow = ((size_t)(b * T_LEN + qrow)) * C_DIM + h * HD;
#pragma unroll
        for (int md = 0; md < 2; md++) {
#pragma unroll
            for (int g = 0; g < 4; g++) {
                uint2 wv;
                wv.x = (unsigned)f2bf(accO[md][g * 4 + 0] * inv) |
                       ((unsigned)f2bf(accO[md][g * 4 + 1] * inv) << 16);
                wv.y = (unsigned)f2bf(accO[md][g * 4 + 2] * inv) |
                       ((unsigned)f2bf(accO[md][g * 4 + 3] * inv) << 16);
                *(uint2*)&attb[orow + md * 32 + 8 * g + 4 * r5] = wv;
            }
        }
    } else {
        const int strip = bh * 8 + (qs - 8);
        const int seg = (k0 != 0) ? 1 : 0;
        float4* pO4 = (float4*)pO;
        const size_t pbase = ((size_t)(strip * 2 + seg) * 4 + w) * 512 + lane;
#pragma unroll
        for (int md = 0; md < 2; md++)
#pragma unroll
            for (int g = 0; g < 4; g++) {
                float4 v4;
                v4.x = accO[md][g * 4 + 0];
                v4.y = accO[md][g * 4 + 1];
                v4.z = accO[md][g * 4 + 2];
                v4.w = accO[md][g * 4 + 3];
                pO4[pbase + (size_t)(md * 4 + g) * 64] = v4;
            }
        pL[(size_t)(strip * 2 + seg) * 256 + w * 64 + lane] = l;
    }
}

// ---------------------------------------------------------------------------
// Combine the two kt-segments of each heavy q-strip: O=(O1+O2)/(l1+l2).
// grid 384 x 256: thread = (strip 0..383, w 0..3, lane 0..63).
// ---------------------------------------------------------------------------
__global__ __launch_bounds__(256) void attn_comb(
    const float* __restrict__ pO, const float* __restrict__ pL,
    unsigned short* __restrict__ attb)
{
    const int g = blockIdx.x * 256 + threadIdx.x;
    const int lane = g & 63, w = (g >> 6) & 3, strip = g >> 8;  // 0..383
    const int r5 = lane >> 5, L31 = lane & 31;
    const int bh = strip >> 3, qs = 8 + (strip & 7);

    const float4* pO4 = (const float4*)pO;
    const size_t b0 = ((size_t)(strip * 2 + 0) * 4 + w) * 512 + lane;
    const size_t b1 = ((size_t)(strip * 2 + 1) * 4 + w) * 512 + lane;
    const float l = pL[(size_t)(strip * 2 + 0) * 256 + w * 64 + lane] +
                    pL[(size_t)(strip * 2 + 1) * 256 + w * 64 + lane];
    const float lt = l + __shfl_xor(l, 32, 64);
    const float inv = __builtin_amdgcn_rcpf(lt);

    const int qrow = qs * 128 + w * 32 + L31;
    const int b = bh / NH, h = bh % NH;
    const size_t orow = ((size_t)(b * T_LEN + qrow)) * C_DIM + h * HD;
#pragma unroll
    for (int md = 0; md < 2; md++)
#pragma unroll
        for (int gq = 0; gq < 4; gq++) {
            const size_t e = (size_t)(md * 4 + gq) * 64;
            float4 v1 = pO4[b0 + e];
            float4 v2 = pO4[b1 + e];
            uint2 wv;
            wv.x = (unsigned)f2bf((v1.x + v2.x) * inv) |
                   ((unsigned)f2bf((v1.y + v2.y) * inv) << 16);
            wv.y = (unsigned)f2bf((v1.z + v2.z) * inv) |
                   ((unsigned)f2bf((v1.w + v2.w) * inv) << 16);
            *(uint2*)&attb[orow + md * 32 + 8 * gq + 4 * r5] = wv;
        }
}

extern "C" void kernel_launch(void* const* d_in, const int* in_sizes, int n_in,
                              void* d_out, int out_size, void* d_ws, size_t ws_size,
                              hipStream_t stream)
{
    const float* x  = (const float*)d_in[0];
    const float* Wq = (const float*)d_in[1];
    const float* bq = (const float*)d_in[2];
    const float* Wk = (const float*)d_in[3];
    const float* bk = (const float*)d_in[4];
    const float* Wv = (const float*)d_in[5];
    const float* bv = (const float*)d_in[6];
    const float* Wo = (const float*)d_in[7];
    const float* bo = (const float*)d_in[8];
    float* out = (float*)d_out;

    const size_t nMC = (size_t)M_ROWS * C_DIM;  // 6291456
    unsigned short* xb   = (unsigned short*)d_ws;
    unsigned short* Wt   = xb + nMC;
    unsigned short* qg   = Wt + 4 * (size_t)WSZ;
    unsigned short* kg   = qg + nMC;
    unsigned short* vtg  = kg + nMC;
    unsigned short* attb = vtg + nMC;
    // scratch reuse: pO = d_out (25.2MB, overwritten by final GEMM);
    // pL lives in the dead xb region (xb unused after gemm_qkv).
    float* pO = out;
    float* pL = (float*)xb;

    conv_x<<<(int)(nMC / 1024), 256, 0, stream>>>(x, xb);
    conv_wt<<<dim3(24, 24, 4), 256, 0, stream>>>(Wq, Wk, Wv, Wo, Wt);
    gemm_tile<192, 0><<<768, 256, 0, stream>>>(xb, Wt, bq, bk, bv,
                                               qg, kg, vtg, nullptr);
    attn_part<<<24 * B_SZ * NH, 256, 0, stream>>>(qg, kg, vtg, attb, pO, pL);
    attn_comb<<<384, 256, 0, stream>>>(pO, pL, attb);
    gemm_tile<96, 1><<<512, 256, 0, stream>>>(attb, Wt + 3 * (size_t)WSZ,
                                              bo, bo, bo, nullptr, nullptr,
                                              nullptr, out);
}